// Round 13
// baseline (222.003 us; speedup 1.0000x reference)
//
#include <hip/hip_runtime.h>
#include <hip/hip_bf16.h>

// LightGCN on MI355X — round 12: best-of configuration.
// spmm8 = R7 exact (8-lane groups, 8-gather loop, no permutation — the
// fastest of 4 measured spmm structures at ~61 µs/layer, bound by the
// L2-miss path for random 128 B row gathers).
// Build = R11's cheap path (boundary-fill rpu, LDS bucket sort for item CSR),
// minus all degree-sort machinery (falsified in R11).

constexpr int N_USERS = 100000;
constexpr int N_ITEMS = 50000;
constexpr int N_NODES = N_USERS + N_ITEMS;
constexpr int D = 64;
constexpr int NBK  = 196;
constexpr int SLOT = 12288;
constexpr int EPB  = 16384;

typedef unsigned int uint4v  __attribute__((ext_vector_type(4)));
typedef float        float4v __attribute__((ext_vector_type(4)));

__device__ inline unsigned f2bf(float f) {
    unsigned u = __float_as_uint(f);
    u += 0x7FFFu + ((u >> 16) & 1u);   // RNE
    return u >> 16;
}
__device__ inline float bflo(unsigned u) { return __uint_as_float(u << 16); }
__device__ inline float bfhi(unsigned u) { return __uint_as_float(u & 0xFFFF0000u); }

// ---- rpu via boundary fill over sorted rows[0:Eh]; also init bcur ----
__global__ __launch_bounds__(256) void edge_bounds(
    const int* __restrict__ rows, int* __restrict__ rpu,
    int* __restrict__ bcur, int Eh)
{
    if (blockIdx.x == 0 && threadIdx.x < NBK) bcur[threadIdx.x] = threadIdx.x * SLOT;
    int j = blockIdx.x * 256 + threadIdx.x;
    if (j >= Eh) return;
    int r = rows[j];
    int rprev = (j == 0) ? -1 : rows[j - 1];
    for (int k = rprev + 1; k <= r; ++k) rpu[k] = j;
    if (j == Eh - 1)
        for (int k = r + 1; k <= N_USERS; ++k) rpu[k] = Eh;
}

// ---- user dinv ----
__global__ __launch_bounds__(256) void user_dinv(
    const int* __restrict__ rpu, float* __restrict__ dinv)
{
    int i = blockIdx.x * 256 + threadIdx.x;
    if (i < N_USERS)
        dinv[i] = rsqrtf((float)(rpu[i + 1] - rpu[i]) + 1e-7f);
}

// ---- pass 1: bucket scatter of (u, vlocal) from the first edge half ----
__global__ __launch_bounds__(256) void bucket_scatter(
    const int* __restrict__ rows, const int* __restrict__ cols,
    int* __restrict__ bcur, int* __restrict__ staging, int Eh)
{
    __shared__ int hist[256];
    const int tid = threadIdx.x;
    const int base = blockIdx.x * EPB;
    const int nEdge = min(EPB, Eh - base);
    if (nEdge <= 0) return;

    hist[tid] = 0;
    __syncthreads();

    for (int s = 0; s < 16; ++s) {
        int o = s * 1024 + tid * 4;
        if (o + 3 < nEdge) {
            int4 c4 = *reinterpret_cast<const int4*>(cols + base + o);
            atomicAdd(&hist[(c4.x - N_USERS) >> 8], 1);
            atomicAdd(&hist[(c4.y - N_USERS) >> 8], 1);
            atomicAdd(&hist[(c4.z - N_USERS) >> 8], 1);
            atomicAdd(&hist[(c4.w - N_USERS) >> 8], 1);
        } else if (o < nEdge) {
            for (int k = o; k < nEdge; ++k)
                atomicAdd(&hist[(cols[base + k] - N_USERS) >> 8], 1);
        }
    }
    __syncthreads();

    if (tid < NBK) {
        int h = hist[tid];
        hist[tid] = (h > 0) ? atomicAdd(&bcur[tid], h) : 0;
    }
    __syncthreads();

    for (int s = 0; s < 16; ++s) {
        int o = s * 1024 + tid * 4;
        if (o + 3 < nEdge) {
            int4 c4 = *reinterpret_cast<const int4*>(cols + base + o);
            int4 u4 = *reinterpret_cast<const int4*>(rows + base + o);
            int v, p;
            v = c4.x - N_USERS; p = atomicAdd(&hist[v >> 8], 1);
            staging[p] = ((v & 255) << 24) | u4.x;
            v = c4.y - N_USERS; p = atomicAdd(&hist[v >> 8], 1);
            staging[p] = ((v & 255) << 24) | u4.y;
            v = c4.z - N_USERS; p = atomicAdd(&hist[v >> 8], 1);
            staging[p] = ((v & 255) << 24) | u4.z;
            v = c4.w - N_USERS; p = atomicAdd(&hist[v >> 8], 1);
            staging[p] = ((v & 255) << 24) | u4.w;
        } else if (o < nEdge) {
            for (int k = o; k < nEdge; ++k) {
                int v = cols[base + k] - N_USERS;
                int u = rows[base + k];
                int p = atomicAdd(&hist[v >> 8], 1);
                staging[p] = ((v & 255) << 24) | u;
            }
        }
    }
}

// ---- pass 2: per-bucket sort -> item CSR + rpi + item dinv (scan fused) ----
__global__ __launch_bounds__(256) void item_csr(
    const int* __restrict__ bcur, const int* __restrict__ staging,
    int* __restrict__ rpi, float* __restrict__ dinv, int* __restrict__ csr)
{
    __shared__ int hist[256];
    __shared__ int cur[256];
    __shared__ int wsum[4];
    __shared__ int s_cbase;
    const int b = blockIdx.x;
    const int tid = threadIdx.x, lane = tid & 63, w = tid >> 6;

    int tot = (tid < NBK) ? (bcur[tid] - tid * SLOT) : 0;
    int incl = tot;
    #pragma unroll
    for (int off = 1; off < 64; off <<= 1) {
        int s = __shfl_up(incl, off);
        if (lane >= off) incl += s;
    }
    if (lane == 63) wsum[w] = incl;
    __syncthreads();
    int woff = 0;
    #pragma unroll
    for (int k = 0; k < 4; ++k) woff += (k < w) ? wsum[k] : 0;
    int excl = woff + incl - tot;
    if (tid == b) s_cbase = excl;
    if (b == 0 && tid == NBK - 1) rpi[N_ITEMS] = excl + tot;
    __syncthreads();

    const int sbase = b * SLOT;
    const int n = bcur[b] - sbase;
    const int cbase = s_cbase;

    hist[tid] = 0;
    __syncthreads();
    for (int i = tid; i < n; i += 256)
        atomicAdd(&hist[((unsigned)staging[sbase + i]) >> 24], 1);
    __syncthreads();

    int h = hist[tid];
    int incl2 = h;
    #pragma unroll
    for (int off = 1; off < 64; off <<= 1) {
        int s = __shfl_up(incl2, off);
        if (lane >= off) incl2 += s;
    }
    if (lane == 63) wsum[w] = incl2;
    __syncthreads();
    int woff2 = 0;
    #pragma unroll
    for (int k = 0; k < 4; ++k) woff2 += (k < w) ? wsum[k] : 0;
    int excl2 = woff2 + incl2 - h;

    int gitem = b * 256 + tid;
    if (gitem < N_ITEMS) {
        rpi[gitem] = cbase + excl2;
        dinv[N_USERS + gitem] = rsqrtf((float)h + 1e-7f);
    }
    cur[tid] = cbase + excl2;
    __syncthreads();

    for (int i = tid; i < n; i += 256) {
        int e = staging[sbase + i];
        int p = atomicAdd(&cur[((unsigned)e) >> 24], 1);
        csr[p] = e & 0xFFFFFF;
    }
}

// ---- prep: z0[r] = dinv[r] * in_embs[r] in bf16 ----
__global__ __launch_bounds__(256) void prep0(
    const float* __restrict__ init, const float* __restrict__ dinv,
    unsigned short* __restrict__ z)
{
    int i = blockIdx.x * 256 + threadIdx.x;     // uint2 (4 bf16) per thread
    if (i >= N_NODES * 16) return;
    int r = i >> 4;
    float dv = dinv[r];
    float4 x = reinterpret_cast<const float4*>(init)[i];
    unsigned lo0 = f2bf(x.x * dv), hi0 = f2bf(x.y * dv);
    unsigned lo1 = f2bf(x.z * dv), hi1 = f2bf(x.w * dv);
    uint2 o; o.x = lo0 | (hi0 << 16); o.y = lo1 | (hi1 << 16);
    reinterpret_cast<uint2*>(z)[i] = o;
}

// ---- fused SpMM + L2-normalize (+ z write | final combine) — R7 exact ----
// 256 threads = 4 waves = 32 rows; 8-lane groups; uint4 (8 dims) per lane.
#define ACC8(r) do { \
    a0 += bflo(r.x); a1 += bfhi(r.x); \
    a2 += bflo(r.y); a3 += bfhi(r.y); \
    a4 += bflo(r.z); a5 += bfhi(r.z); \
    a6 += bflo(r.w); a7 += bfhi(r.w); } while (0)

template<int LAST>
__global__ __launch_bounds__(256) void spmm8(
    const unsigned short* __restrict__ z,
    const int* __restrict__ rpu,
    const int* __restrict__ rpi,
    const int* __restrict__ cols_u,
    const int* __restrict__ csr_col_i,
    const float* __restrict__ dinv,
    unsigned short* __restrict__ zout,
    const unsigned short* z1,
    const unsigned short* z2,
    const float* __restrict__ init,
    float* __restrict__ out)
{
    const int tid = threadIdx.x;
    const int lane = tid & 63;
    const int g  = lane >> 3;
    const int sl = lane & 7;
    const int wave = tid >> 6;
    const int row = blockIdx.x * 32 + wave * 8 + g;
    if (row >= N_NODES) return;
    const int gb = g << 3;

    int beg, end;
    const int* clist;
    if (row < N_USERS) {
        beg = rpu[row]; end = rpu[row + 1]; clist = cols_u;
    } else {
        int v = row - N_USERS;
        beg = rpi[v]; end = rpi[v + 1]; clist = csr_col_i;
    }

    float a0=0.f,a1=0.f,a2=0.f,a3=0.f,a4=0.f,a5=0.f,a6=0.f,a7=0.f;
    const unsigned short* zs = z + (size_t)sl * 8;

    int j = beg;
    for (; j + 8 <= end; j += 8) {
        int c_l = clist[j + sl];
        int c0 = __shfl(c_l, gb + 0);
        int c1 = __shfl(c_l, gb + 1);
        int c2 = __shfl(c_l, gb + 2);
        int c3 = __shfl(c_l, gb + 3);
        int c4 = __shfl(c_l, gb + 4);
        int c5 = __shfl(c_l, gb + 5);
        int c6 = __shfl(c_l, gb + 6);
        int c7 = __shfl(c_l, gb + 7);
        uint4 r0 = *reinterpret_cast<const uint4*>(zs + (size_t)c0 * D);
        uint4 r1 = *reinterpret_cast<const uint4*>(zs + (size_t)c1 * D);
        uint4 r2 = *reinterpret_cast<const uint4*>(zs + (size_t)c2 * D);
        uint4 r3 = *reinterpret_cast<const uint4*>(zs + (size_t)c3 * D);
        uint4 r4 = *reinterpret_cast<const uint4*>(zs + (size_t)c4 * D);
        uint4 r5 = *reinterpret_cast<const uint4*>(zs + (size_t)c5 * D);
        uint4 r6 = *reinterpret_cast<const uint4*>(zs + (size_t)c6 * D);
        uint4 r7 = *reinterpret_cast<const uint4*>(zs + (size_t)c7 * D);
        ACC8(r0); ACC8(r1); ACC8(r2); ACC8(r3);
        ACC8(r4); ACC8(r5); ACC8(r6); ACC8(r7);
    }
    int rem = end - j;
    if (rem > 0) {
        int c_l = (j + sl < end) ? clist[j + sl] : 0;
        for (int k = 0; k < rem; ++k) {
            int c = __shfl(c_l, gb + k);
            uint4 r = *reinterpret_cast<const uint4*>(zs + (size_t)c * D);
            ACC8(r);
        }
    }

    float ss = a0*a0 + a1*a1 + a2*a2 + a3*a3 + a4*a4 + a5*a5 + a6*a6 + a7*a7;
    ss += __shfl_xor(ss, 1);
    ss += __shfl_xor(ss, 2);
    ss += __shfl_xor(ss, 4);
    float rinv = 1.0f / fmaxf(sqrtf(ss), 1e-12f);

    size_t idx = (size_t)row * D + (size_t)sl * 8;
    if (!LAST) {
        float sc = rinv * dinv[row];
        uint4 zo;
        zo.x = f2bf(a0 * sc) | (f2bf(a1 * sc) << 16);
        zo.y = f2bf(a2 * sc) | (f2bf(a3 * sc) << 16);
        zo.z = f2bf(a4 * sc) | (f2bf(a5 * sc) << 16);
        zo.w = f2bf(a6 * sc) | (f2bf(a7 * sc) << 16);
        *reinterpret_cast<uint4*>(zout + idx) = zo;
    } else {
        float recip = 1.0f / dinv[row];          // = sqrt(deg + eps)
        float k1 = recip, k2 = 0.5f * recip, k3 = rinv * (1.0f / 3.0f);
        uint4v w1 = __builtin_nontemporal_load(reinterpret_cast<const uint4v*>(z1 + idx));
        uint4v w2 = __builtin_nontemporal_load(reinterpret_cast<const uint4v*>(z2 + idx));
        const float4v* ip = reinterpret_cast<const float4v*>(init + idx);
        float4v o0 = __builtin_nontemporal_load(ip);
        float4v o1 = __builtin_nontemporal_load(ip + 1);
        o0.x += bflo(w1.x) * k1 + bflo(w2.x) * k2 + a0 * k3;
        o0.y += bfhi(w1.x) * k1 + bfhi(w2.x) * k2 + a1 * k3;
        o0.z += bflo(w1.y) * k1 + bflo(w2.y) * k2 + a2 * k3;
        o0.w += bfhi(w1.y) * k1 + bfhi(w2.y) * k2 + a3 * k3;
        o1.x += bflo(w1.z) * k1 + bflo(w2.z) * k2 + a4 * k3;
        o1.y += bfhi(w1.z) * k1 + bfhi(w2.z) * k2 + a5 * k3;
        o1.z += bflo(w1.w) * k1 + bflo(w2.w) * k2 + a6 * k3;
        o1.w += bfhi(w1.w) * k1 + bfhi(w2.w) * k2 + a7 * k3;
        float4v* op = reinterpret_cast<float4v*>(out + idx);
        __builtin_nontemporal_store(o0, op);
        __builtin_nontemporal_store(o1, op + 1);
    }
}

extern "C" void kernel_launch(void* const* d_in, const int* in_sizes, int n_in,
                              void* d_out, int out_size, void* d_ws, size_t ws_size,
                              hipStream_t stream) {
    const float* in_embs = (const float*)d_in[0];
    const int*   rows    = (const int*)d_in[1];
    const int*   cols    = (const int*)d_in[2];
    float* out = (float*)d_out;

    const int E  = in_sizes[1];
    const int Eh = E / 2;
    const size_t z_bytes = (size_t)N_NODES * D * sizeof(unsigned short); // 19.2 MB

    auto align256 = [](size_t x) { return (x + 255) & ~(size_t)255; };
    char* p = (char*)d_ws;
    unsigned short* zP = (unsigned short*)p; p += align256(z_bytes);
    unsigned short* zQ = (unsigned short*)p; p += align256(z_bytes);
    int*   csr_col_i = (int*)p;   p += align256((size_t)Eh * sizeof(int));
    int*   rpu       = (int*)p;   p += align256((size_t)(N_USERS + 1) * sizeof(int));
    int*   rpi       = (int*)p;   p += align256((size_t)(N_ITEMS + 1) * sizeof(int));
    float* dinv      = (float*)p; p += align256((size_t)N_NODES * sizeof(float));
    int*   bcur      = (int*)p;   p += align256(256 * sizeof(int));
    // staging aliases zP (9.63 MB < 19.2 MB); consumed by item_csr before prep0
    int*   staging   = (int*)zP;

    // --- CSR build (5 dispatches) ---
    edge_bounds<<<(Eh + 255) / 256, 256, 0, stream>>>(rows, rpu, bcur, Eh);
    user_dinv<<<(N_USERS + 255) / 256, 256, 0, stream>>>(rpu, dinv);
    bucket_scatter<<<(Eh + EPB - 1) / EPB, 256, 0, stream>>>(rows, cols, bcur, staging, Eh);
    item_csr<<<NBK, 256, 0, stream>>>(bcur, staging, rpi, dinv, csr_col_i);
    prep0<<<(N_NODES * 16 + 255) / 256, 256, 0, stream>>>(in_embs, dinv, zP);

    // --- 3 propagation layers ---
    const int grid = (N_NODES + 31) / 32;
    spmm8<0><<<grid, 256, 0, stream>>>(zP, rpu, rpi, cols, csr_col_i, dinv,
                                       zQ, nullptr, nullptr, nullptr, nullptr);
    spmm8<0><<<grid, 256, 0, stream>>>(zQ, rpu, rpi, cols, csr_col_i, dinv,
                                       zP, nullptr, nullptr, nullptr, nullptr);
    spmm8<1><<<grid, 256, 0, stream>>>(zP, rpu, rpi, cols, csr_col_i, dinv,
                                       nullptr, zQ, zP, in_embs, out);
}

// Round 14
// 217.494 us; speedup vs baseline: 1.0207x; 1.0207x over previous
//
#include <hip/hip_runtime.h>
#include <hip/hip_bf16.h>

// LightGCN on MI355X — round 14.
// spmm8 = R7/R12 exact (measured floor: 59 µs/layer across 4 structural
// variants; bound by random 128 B gathers from a 19.2 MB bf16 working set).
// Build tightened: EPB 16384->4096 (98->391 blocks, CU-saturating scatter);
// user dinv fused into prep0 (one fewer dispatch).

constexpr int N_USERS = 100000;
constexpr int N_ITEMS = 50000;
constexpr int N_NODES = N_USERS + N_ITEMS;
constexpr int D = 64;
constexpr int NBK  = 196;
constexpr int SLOT = 12288;
constexpr int EPB  = 4096;        // 391 blocks -> all CUs busy

typedef unsigned int uint4v  __attribute__((ext_vector_type(4)));
typedef float        float4v __attribute__((ext_vector_type(4)));

__device__ inline unsigned f2bf(float f) {
    unsigned u = __float_as_uint(f);
    u += 0x7FFFu + ((u >> 16) & 1u);   // RNE
    return u >> 16;
}
__device__ inline float bflo(unsigned u) { return __uint_as_float(u << 16); }
__device__ inline float bfhi(unsigned u) { return __uint_as_float(u & 0xFFFF0000u); }

// ---- rpu via boundary fill over sorted rows[0:Eh]; also init bcur ----
__global__ __launch_bounds__(256) void edge_bounds(
    const int* __restrict__ rows, int* __restrict__ rpu,
    int* __restrict__ bcur, int Eh)
{
    if (blockIdx.x == 0 && threadIdx.x < NBK) bcur[threadIdx.x] = threadIdx.x * SLOT;
    int j = blockIdx.x * 256 + threadIdx.x;
    if (j >= Eh) return;
    int r = rows[j];
    int rprev = (j == 0) ? -1 : rows[j - 1];
    for (int k = rprev + 1; k <= r; ++k) rpu[k] = j;
    if (j == Eh - 1)
        for (int k = r + 1; k <= N_USERS; ++k) rpu[k] = Eh;
}

// ---- pass 1: bucket scatter of (u, vlocal) from the first edge half ----
__global__ __launch_bounds__(256) void bucket_scatter(
    const int* __restrict__ rows, const int* __restrict__ cols,
    int* __restrict__ bcur, int* __restrict__ staging, int Eh)
{
    __shared__ int hist[256];
    const int tid = threadIdx.x;
    const int base = blockIdx.x * EPB;
    const int nEdge = min(EPB, Eh - base);
    if (nEdge <= 0) return;

    hist[tid] = 0;
    __syncthreads();

    for (int s = 0; s < EPB / 1024; ++s) {
        int o = s * 1024 + tid * 4;
        if (o + 3 < nEdge) {
            int4 c4 = *reinterpret_cast<const int4*>(cols + base + o);
            atomicAdd(&hist[(c4.x - N_USERS) >> 8], 1);
            atomicAdd(&hist[(c4.y - N_USERS) >> 8], 1);
            atomicAdd(&hist[(c4.z - N_USERS) >> 8], 1);
            atomicAdd(&hist[(c4.w - N_USERS) >> 8], 1);
        } else if (o < nEdge) {
            for (int k = o; k < nEdge; ++k)
                atomicAdd(&hist[(cols[base + k] - N_USERS) >> 8], 1);
        }
    }
    __syncthreads();

    if (tid < NBK) {
        int h = hist[tid];
        hist[tid] = (h > 0) ? atomicAdd(&bcur[tid], h) : 0;
    }
    __syncthreads();

    for (int s = 0; s < EPB / 1024; ++s) {
        int o = s * 1024 + tid * 4;
        if (o + 3 < nEdge) {
            int4 c4 = *reinterpret_cast<const int4*>(cols + base + o);
            int4 u4 = *reinterpret_cast<const int4*>(rows + base + o);
            int v, p;
            v = c4.x - N_USERS; p = atomicAdd(&hist[v >> 8], 1);
            staging[p] = ((v & 255) << 24) | u4.x;
            v = c4.y - N_USERS; p = atomicAdd(&hist[v >> 8], 1);
            staging[p] = ((v & 255) << 24) | u4.y;
            v = c4.z - N_USERS; p = atomicAdd(&hist[v >> 8], 1);
            staging[p] = ((v & 255) << 24) | u4.z;
            v = c4.w - N_USERS; p = atomicAdd(&hist[v >> 8], 1);
            staging[p] = ((v & 255) << 24) | u4.w;
        } else if (o < nEdge) {
            for (int k = o; k < nEdge; ++k) {
                int v = cols[base + k] - N_USERS;
                int u = rows[base + k];
                int p = atomicAdd(&hist[v >> 8], 1);
                staging[p] = ((v & 255) << 24) | u;
            }
        }
    }
}

// ---- pass 2: per-bucket sort -> item CSR + rpi + item dinv (scan fused) ----
__global__ __launch_bounds__(256) void item_csr(
    const int* __restrict__ bcur, const int* __restrict__ staging,
    int* __restrict__ rpi, float* __restrict__ dinv, int* __restrict__ csr)
{
    __shared__ int hist[256];
    __shared__ int cur[256];
    __shared__ int wsum[4];
    __shared__ int s_cbase;
    const int b = blockIdx.x;
    const int tid = threadIdx.x, lane = tid & 63, w = tid >> 6;

    int tot = (tid < NBK) ? (bcur[tid] - tid * SLOT) : 0;
    int incl = tot;
    #pragma unroll
    for (int off = 1; off < 64; off <<= 1) {
        int s = __shfl_up(incl, off);
        if (lane >= off) incl += s;
    }
    if (lane == 63) wsum[w] = incl;
    __syncthreads();
    int woff = 0;
    #pragma unroll
    for (int k = 0; k < 4; ++k) woff += (k < w) ? wsum[k] : 0;
    int excl = woff + incl - tot;
    if (tid == b) s_cbase = excl;
    if (b == 0 && tid == NBK - 1) rpi[N_ITEMS] = excl + tot;
    __syncthreads();

    const int sbase = b * SLOT;
    const int n = bcur[b] - sbase;
    const int cbase = s_cbase;

    hist[tid] = 0;
    __syncthreads();
    for (int i = tid; i < n; i += 256)
        atomicAdd(&hist[((unsigned)staging[sbase + i]) >> 24], 1);
    __syncthreads();

    int h = hist[tid];
    int incl2 = h;
    #pragma unroll
    for (int off = 1; off < 64; off <<= 1) {
        int s = __shfl_up(incl2, off);
        if (lane >= off) incl2 += s;
    }
    if (lane == 63) wsum[w] = incl2;
    __syncthreads();
    int woff2 = 0;
    #pragma unroll
    for (int k = 0; k < 4; ++k) woff2 += (k < w) ? wsum[k] : 0;
    int excl2 = woff2 + incl2 - h;

    int gitem = b * 256 + tid;
    if (gitem < N_ITEMS) {
        rpi[gitem] = cbase + excl2;
        dinv[N_USERS + gitem] = rsqrtf((float)h + 1e-7f);
    }
    cur[tid] = cbase + excl2;
    __syncthreads();

    for (int i = tid; i < n; i += 256) {
        int e = staging[sbase + i];
        int p = atomicAdd(&cur[((unsigned)e) >> 24], 1);
        csr[p] = e & 0xFFFFFF;
    }
}

// ---- prep: user dinv (from rpu) + z0[r] = dinv[r]*in_embs[r] in bf16 ----
__global__ __launch_bounds__(256) void prep0(
    const float* __restrict__ init, const int* __restrict__ rpu,
    float* __restrict__ dinv, unsigned short* __restrict__ z)
{
    int i = blockIdx.x * 256 + threadIdx.x;     // uint2 (4 bf16) per thread
    if (i >= N_NODES * 16) return;
    int r = i >> 4;
    float dv;
    if (r < N_USERS) {
        dv = rsqrtf((float)(rpu[r + 1] - rpu[r]) + 1e-7f);
        if ((i & 15) == 0) dinv[r] = dv;
    } else {
        dv = dinv[r];
    }
    float4 x = reinterpret_cast<const float4*>(init)[i];
    unsigned lo0 = f2bf(x.x * dv), hi0 = f2bf(x.y * dv);
    unsigned lo1 = f2bf(x.z * dv), hi1 = f2bf(x.w * dv);
    uint2 o; o.x = lo0 | (hi0 << 16); o.y = lo1 | (hi1 << 16);
    reinterpret_cast<uint2*>(z)[i] = o;
}

// ---- fused SpMM + L2-normalize (+ z write | final combine) — R7 exact ----
// 256 threads = 4 waves = 32 rows; 8-lane groups; uint4 (8 dims) per lane.
#define ACC8(r) do { \
    a0 += bflo(r.x); a1 += bfhi(r.x); \
    a2 += bflo(r.y); a3 += bfhi(r.y); \
    a4 += bflo(r.z); a5 += bfhi(r.z); \
    a6 += bflo(r.w); a7 += bfhi(r.w); } while (0)

template<int LAST>
__global__ __launch_bounds__(256) void spmm8(
    const unsigned short* __restrict__ z,
    const int* __restrict__ rpu,
    const int* __restrict__ rpi,
    const int* __restrict__ cols_u,
    const int* __restrict__ csr_col_i,
    const float* __restrict__ dinv,
    unsigned short* __restrict__ zout,
    const unsigned short* z1,
    const unsigned short* z2,
    const float* __restrict__ init,
    float* __restrict__ out)
{
    const int tid = threadIdx.x;
    const int lane = tid & 63;
    const int g  = lane >> 3;
    const int sl = lane & 7;
    const int wave = tid >> 6;
    const int row = blockIdx.x * 32 + wave * 8 + g;
    if (row >= N_NODES) return;
    const int gb = g << 3;

    int beg, end;
    const int* clist;
    if (row < N_USERS) {
        beg = rpu[row]; end = rpu[row + 1]; clist = cols_u;
    } else {
        int v = row - N_USERS;
        beg = rpi[v]; end = rpi[v + 1]; clist = csr_col_i;
    }

    float a0=0.f,a1=0.f,a2=0.f,a3=0.f,a4=0.f,a5=0.f,a6=0.f,a7=0.f;
    const unsigned short* zs = z + (size_t)sl * 8;

    int j = beg;
    for (; j + 8 <= end; j += 8) {
        int c_l = clist[j + sl];
        int c0 = __shfl(c_l, gb + 0);
        int c1 = __shfl(c_l, gb + 1);
        int c2 = __shfl(c_l, gb + 2);
        int c3 = __shfl(c_l, gb + 3);
        int c4 = __shfl(c_l, gb + 4);
        int c5 = __shfl(c_l, gb + 5);
        int c6 = __shfl(c_l, gb + 6);
        int c7 = __shfl(c_l, gb + 7);
        uint4 r0 = *reinterpret_cast<const uint4*>(zs + (size_t)c0 * D);
        uint4 r1 = *reinterpret_cast<const uint4*>(zs + (size_t)c1 * D);
        uint4 r2 = *reinterpret_cast<const uint4*>(zs + (size_t)c2 * D);
        uint4 r3 = *reinterpret_cast<const uint4*>(zs + (size_t)c3 * D);
        uint4 r4 = *reinterpret_cast<const uint4*>(zs + (size_t)c4 * D);
        uint4 r5 = *reinterpret_cast<const uint4*>(zs + (size_t)c5 * D);
        uint4 r6 = *reinterpret_cast<const uint4*>(zs + (size_t)c6 * D);
        uint4 r7 = *reinterpret_cast<const uint4*>(zs + (size_t)c7 * D);
        ACC8(r0); ACC8(r1); ACC8(r2); ACC8(r3);
        ACC8(r4); ACC8(r5); ACC8(r6); ACC8(r7);
    }
    int rem = end - j;
    if (rem > 0) {
        int c_l = (j + sl < end) ? clist[j + sl] : 0;
        for (int k = 0; k < rem; ++k) {
            int c = __shfl(c_l, gb + k);
            uint4 r = *reinterpret_cast<const uint4*>(zs + (size_t)c * D);
            ACC8(r);
        }
    }

    float ss = a0*a0 + a1*a1 + a2*a2 + a3*a3 + a4*a4 + a5*a5 + a6*a6 + a7*a7;
    ss += __shfl_xor(ss, 1);
    ss += __shfl_xor(ss, 2);
    ss += __shfl_xor(ss, 4);
    float rinv = 1.0f / fmaxf(sqrtf(ss), 1e-12f);

    size_t idx = (size_t)row * D + (size_t)sl * 8;
    if (!LAST) {
        float sc = rinv * dinv[row];
        uint4 zo;
        zo.x = f2bf(a0 * sc) | (f2bf(a1 * sc) << 16);
        zo.y = f2bf(a2 * sc) | (f2bf(a3 * sc) << 16);
        zo.z = f2bf(a4 * sc) | (f2bf(a5 * sc) << 16);
        zo.w = f2bf(a6 * sc) | (f2bf(a7 * sc) << 16);
        *reinterpret_cast<uint4*>(zout + idx) = zo;
    } else {
        float recip = 1.0f / dinv[row];          // = sqrt(deg + eps)
        float k1 = recip, k2 = 0.5f * recip, k3 = rinv * (1.0f / 3.0f);
        uint4v w1 = __builtin_nontemporal_load(reinterpret_cast<const uint4v*>(z1 + idx));
        uint4v w2 = __builtin_nontemporal_load(reinterpret_cast<const uint4v*>(z2 + idx));
        const float4v* ip = reinterpret_cast<const float4v*>(init + idx);
        float4v o0 = __builtin_nontemporal_load(ip);
        float4v o1 = __builtin_nontemporal_load(ip + 1);
        o0.x += bflo(w1.x) * k1 + bflo(w2.x) * k2 + a0 * k3;
        o0.y += bfhi(w1.x) * k1 + bfhi(w2.x) * k2 + a1 * k3;
        o0.z += bflo(w1.y) * k1 + bflo(w2.y) * k2 + a2 * k3;
        o0.w += bfhi(w1.y) * k1 + bfhi(w2.y) * k2 + a3 * k3;
        o1.x += bflo(w1.z) * k1 + bflo(w2.z) * k2 + a4 * k3;
        o1.y += bfhi(w1.z) * k1 + bfhi(w2.z) * k2 + a5 * k3;
        o1.z += bflo(w1.w) * k1 + bflo(w2.w) * k2 + a6 * k3;
        o1.w += bfhi(w1.w) * k1 + bfhi(w2.w) * k2 + a7 * k3;
        float4v* op = reinterpret_cast<float4v*>(out + idx);
        __builtin_nontemporal_store(o0, op);
        __builtin_nontemporal_store(o1, op + 1);
    }
}

extern "C" void kernel_launch(void* const* d_in, const int* in_sizes, int n_in,
                              void* d_out, int out_size, void* d_ws, size_t ws_size,
                              hipStream_t stream) {
    const float* in_embs = (const float*)d_in[0];
    const int*   rows    = (const int*)d_in[1];
    const int*   cols    = (const int*)d_in[2];
    float* out = (float*)d_out;

    const int E  = in_sizes[1];
    const int Eh = E / 2;
    const size_t z_bytes = (size_t)N_NODES * D * sizeof(unsigned short); // 19.2 MB

    auto align256 = [](size_t x) { return (x + 255) & ~(size_t)255; };
    char* p = (char*)d_ws;
    unsigned short* zP = (unsigned short*)p; p += align256(z_bytes);
    unsigned short* zQ = (unsigned short*)p; p += align256(z_bytes);
    int*   csr_col_i = (int*)p;   p += align256((size_t)Eh * sizeof(int));
    int*   rpu       = (int*)p;   p += align256((size_t)(N_USERS + 1) * sizeof(int));
    int*   rpi       = (int*)p;   p += align256((size_t)(N_ITEMS + 1) * sizeof(int));
    float* dinv      = (float*)p; p += align256((size_t)N_NODES * sizeof(float));
    int*   bcur      = (int*)p;   p += align256(256 * sizeof(int));
    // staging aliases zP (9.63 MB < 19.2 MB); consumed by item_csr before prep0
    int*   staging   = (int*)zP;

    // --- CSR build (4 dispatches) ---
    edge_bounds<<<(Eh + 255) / 256, 256, 0, stream>>>(rows, rpu, bcur, Eh);
    bucket_scatter<<<(Eh + EPB - 1) / EPB, 256, 0, stream>>>(rows, cols, bcur, staging, Eh);
    item_csr<<<NBK, 256, 0, stream>>>(bcur, staging, rpi, dinv, csr_col_i);
    prep0<<<(N_NODES * 16 + 255) / 256, 256, 0, stream>>>(in_embs, rpu, dinv, zP);

    // --- 3 propagation layers ---
    const int grid = (N_NODES + 31) / 32;
    spmm8<0><<<grid, 256, 0, stream>>>(zP, rpu, rpi, cols, csr_col_i, dinv,
                                       zQ, nullptr, nullptr, nullptr, nullptr);
    spmm8<0><<<grid, 256, 0, stream>>>(zQ, rpu, rpi, cols, csr_col_i, dinv,
                                       zP, nullptr, nullptr, nullptr, nullptr);
    spmm8<1><<<grid, 256, 0, stream>>>(zP, rpu, rpi, cols, csr_col_i, dinv,
                                       nullptr, zQ, zP, in_embs, out);
}